// Round 11
// baseline (284.115 us; speedup 1.0000x reference)
//
#include <hip/hip_runtime.h>
#include <stdint.h>

#define DIN   4096
#define DOUT  4096
#define MTOT  8192
#define NT    64                      /* K-tiles of BK=64 */

#define BM    256
#define BN    256
#define GRID_M (MTOT / BM)            /* 32 */
#define GRID_N (DOUT / BN)            /* 16 */
#define NWG   (GRID_M * GRID_N)       /* 512 */

typedef __attribute__((ext_vector_type(4)))  float        f32x4;
typedef __attribute__((ext_vector_type(16))) float        f32x16;
typedef __attribute__((ext_vector_type(4)))  int          i32x4;
typedef __attribute__((ext_vector_type(4)))  unsigned int u32x4;
typedef __attribute__((ext_vector_type(2)))  unsigned int u32x2;
typedef __attribute__((ext_vector_type(8)))  short        bf16x8;

__device__ __forceinline__ unsigned int pack_bf2_rne(float a, float b) {
  unsigned int ua = __builtin_bit_cast(unsigned int, a);
  unsigned int ub = __builtin_bit_cast(unsigned int, b);
  ua += 0x7fffu + ((ua >> 16) & 1u);
  ub += 0x7fffu + ((ub >> 16) & 1u);
  return (ua >> 16) | (ub & 0xffff0000u);
}

// (w - off) integer, |v| <= 135 < 256 -> exact in bf16.
__device__ __forceinline__ unsigned int pack_bf2_exact(int a, int b) {
  unsigned int ua = __builtin_bit_cast(unsigned int, (float)a);
  unsigned int ub = __builtin_bit_cast(unsigned int, (float)b);
  return (ua >> 16) | (ub & 0xffff0000u);
}

// ---- merged pre-pass (r10, proven): x->bf16 and (w-off)->bf16 into CHUNK-MAJOR
// 16KiB units: byte = ch*2048 + row*16 (ch = 16B k-chunk 0..7, row 0..127).
#define UNITS_A (GRID_M * 2 * NT)
#define UNITS_B (GRID_N * 2 * NT)
__global__ __launch_bounds__(256) void conv_kernel(const float* __restrict__ X,
                                                   u32x4* __restrict__ wsA,
                                                   const int* __restrict__ W,
                                                   const int* __restrict__ Off,
                                                   u32x4* __restrict__ wsB) {
  const int totA = UNITS_A * 1024;
  const int totB = UNITS_B * 1024;
  for (int idx = blockIdx.x * 256 + threadIdx.x; idx < totA + totB;
       idx += gridDim.x * 256) {
    if (idx < totA) {
      const int pos = idx & 1023;
      const int row = pos >> 3, ch = pos & 7;
      const int unit = idx >> 10;
      const int kt = unit & (NT - 1), rb = unit >> 6;
      const int m = rb * 128 + row;
      const f32x4* src = (const f32x4*)(X + ((long)m << 12) + kt * 64 + ch * 8);
      f32x4 f0 = src[0], f1 = src[1];
      u32x4 d;
      d[0] = pack_bf2_rne(f0[0], f0[1]);
      d[1] = pack_bf2_rne(f0[2], f0[3]);
      d[2] = pack_bf2_rne(f1[0], f1[1]);
      d[3] = pack_bf2_rne(f1[2], f1[3]);
      wsA[(long)unit * 1024 + ch * 128 + row] = d;
    } else {
      const int j = idx - totA;
      const int pos = j & 1023;
      const int row = pos >> 3, ch = pos & 7;
      const int unit = j >> 10;
      const int kt = unit & (NT - 1), nb = unit >> 6;
      const int n = nb * 128 + row;
      const i32x4* src = (const i32x4*)(W + ((long)n << 12) + kt * 64 + ch * 8);
      const int off = Off[n];
      i32x4 w0 = src[0], w1 = src[1];
      u32x4 d;
      d[0] = pack_bf2_exact(w0[0] - off, w0[1] - off);
      d[1] = pack_bf2_exact(w0[2] - off, w0[3] - off);
      d[2] = pack_bf2_exact(w1[0] - off, w1[1] - off);
      d[3] = pack_bf2_exact(w1[2] - off, w1[3] - off);
      wsB[(long)unit * 1024 + ch * 128 + row] = d;
    }
  }
}

// ======= B-direct 32x32x16 GEMM: A via LDS (chunk-major), B via per-lane global =======
// LDS demand/tile drops 3070->~1920 cyc (reads 192->128, stage writes halve);
// B moves to the vector-mem/L2 pipe (64 KB/tile/CU ~ 15 B/cyc << L2 56 B/cyc/CU).
// kk-major phases: ph_kk = { 4 A ds_reads (mt0..3 at chunk kk) ; [stage A(t+1)] ;
//   [vmcnt gate] ; cascade 8 MFMA (LGKM 3..0 per mt) ; [BLOAD bR[kk] <- B(t+1)] ; BAR }.
// BLOAD after CASC(kk): bR[kk] dead -> WAR-safe; consumed ph_kk(t+1) (full-tile window).
// vmcnt ledger (issue-then-gate, per wave; 2 loads per STAGE/BLOAD):
//   invariant entering tile t: 6 outstanding = Bk1,Bk2,Bk3(t).
//   ph0: +stA0 ->8; CASC; +Bk0' ->10.       (no gate: Bk0(t) retired last tile)
//   ph1: +stA1 ->12; gate Bk1(t): WAITV(10); CASC; +Bk1' ->12.
//   ph2: gate Bk2(t): WAITV(10); CASC; +Bk2' ->12.
//   ph3: gate Bk3(t): WAITV(10); CASC; +Bk3' ->12; end WAITV(6) retires
//        stA0,Bk0',stA1 -> A(t+1) staging retired BEFORE tile-end BAR
//        (retire->BAR->read holds); leaves Bk1',Bk2',Bk3' = 6. QED.
// Tail tile 63 (no issues): gates 4/2/0. Prologue: stA0,stA1,Bk0..3 -> WAITV(6).
// B needs no barriers (private VGPRs). A-buf WAR: per-phase BARs (r10 argument).

#define BAR()   __builtin_amdgcn_s_barrier()
#define SB()    __builtin_amdgcn_sched_barrier(0)
#define LGKM_(N) asm volatile("s_waitcnt lgkmcnt(" #N ")" ::: "memory")
#define LGKM(N)  LGKM_(N)
#define WAITV(N) asm volatile("s_waitcnt vmcnt(" #N ")" ::: "memory")

typedef __attribute__((address_space(3))) const char* ldsp;

#define DSR(dst, p, IMM) \
  asm volatile("ds_read_b128 %0, %1 offset:" #IMM : "=v"(dst) : "v"(p))

#define STAGE(bufc, h, basePtr, t)                                              \
  { const u32x4* s_ = (basePtr) + (long)(t) * 1024;                             \
    _Pragma("unroll")                                                           \
    for (int i_ = 0; i_ < 2; ++i_) {                                            \
      const int o_ = tid + i_ * 512;                                            \
      __builtin_amdgcn_global_load_lds(                                         \
          (const __attribute__((address_space(1))) void*)(s_ + o_),             \
          (__attribute__((address_space(3))) void*)(&ldsA[bufc][h][0] + o_),    \
          16, 0, 0);                                                            \
    } }

// B(t+1)[kk]: two coalesced 16B per-lane loads (nt=0,1) straight from wsB
#define BLOAD(kk, t)                                                            \
  { const char* pk_ = bBw + (long)((t) + 1) * 16384 + (kk) * 4096;              \
    asm volatile("global_load_dwordx4 %0, %1, off"                              \
                 : "=v"(bR[kk][0]) : "v"(pk_));                                 \
    asm volatile("global_load_dwordx4 %0, %1, off offset:512"                   \
                 : "=v"(bR[kk][1]) : "v"(pk_)); }

// 4 A frags (mt=0..3) at chunk kk: offsets kk*4096 + mt*512
#define RD_A4(pA_, O0, O1, O2, O3)                                              \
  DSR(aR[0], pA_, O0); DSR(aR[1], pA_, O1);                                     \
  DSR(aR[2], pA_, O2); DSR(aR[3], pA_, O3);

#define MMA2(mt, kk)                                                            \
  acc[mt][0] = __builtin_amdgcn_mfma_f32_32x32x16_bf16(aR[mt], bR[kk][0],       \
                                                       acc[mt][0], 0, 0, 0);    \
  acc[mt][1] = __builtin_amdgcn_mfma_f32_32x32x16_bf16(aR[mt], bR[kk][1],       \
                                                       acc[mt][1], 0, 0, 0);

#define CASC(kk)                                                                \
  __builtin_amdgcn_s_setprio(1);                                                \
  LGKM(3); SB(); MMA2(0, kk)                                                    \
  LGKM(2); SB(); MMA2(1, kk)                                                    \
  LGKM(1); SB(); MMA2(2, kk)                                                    \
  LGKM(0); SB(); MMA2(3, kk)                                                    \
  __builtin_amdgcn_s_setprio(0);

#define TILE(pA_, ABUF, t, SG, W1, W2, W3, WE)                                  \
  RD_A4(pA_, 0, 512, 1024, 1536)                                                \
  if (SG) { STAGE(ABUF, 0, bA0, (t) + 1) }                                      \
  CASC(0)                                                                       \
  if (SG) { BLOAD(0, t) }                                                       \
  BAR();                                                                        \
  RD_A4(pA_, 4096, 4608, 5120, 5632)                                            \
  if (SG) { STAGE(ABUF, 1, bA1, (t) + 1) }                                      \
  W1; CASC(1)                                                                   \
  if (SG) { BLOAD(1, t) }                                                       \
  BAR();                                                                        \
  RD_A4(pA_, 8192, 8704, 9216, 9728)                                            \
  W2; CASC(2)                                                                   \
  if (SG) { BLOAD(2, t) }                                                       \
  BAR();                                                                        \
  RD_A4(pA_, 12288, 12800, 13312, 13824)                                        \
  W3; CASC(3)                                                                   \
  if (SG) { BLOAD(3, t) }                                                       \
  WE; BAR();

__global__ __launch_bounds__(512, 2) void gemm8_kernel(
    const u32x4* __restrict__ wsA, const u32x4* __restrict__ wsB,
    const float* __restrict__ Scale, float* __restrict__ Out) {
  __shared__ u32x4 ldsA[2][2][1024];   // A only: [buf][unit][ch*128+row] = 32 KiB x2

  const int tid  = threadIdx.x;
  const int lane = tid & 63;
  const int wid  = tid >> 6;
  const int wr   = wid >> 2;     // A unit (128-row half)
  const int wc   = wid & 3;      // 64-col N slice
  const int wch  = wc >> 1;      // B unit
  const int wcl  = wc & 1;
  const int lane31 = lane & 31;
  const int lhi    = lane >> 5;

  int gid = (int)blockIdx.x;
  gid = (gid & 7) * (NWG >> 3) + (gid >> 3);   // bijective XCD swizzle (512%8==0)
  const int wg_m = gid / GRID_N;
  const int wg_n = gid % GRID_N;

  const int lanepA = lane31 * 16 + lhi * 2048;

  ldsp pA0 = (ldsp)((const char*)&ldsA[0][wr][0] + lanepA);
  ldsp pA1 = (ldsp)((const char*)&ldsA[1][wr][0] + lanepA);

  const u32x4* bA0 = wsA + (long)(wg_m * 2 + 0) * NT * 1024;
  const u32x4* bA1 = wsA + (long)(wg_m * 2 + 1) * NT * 1024;
  // per-lane B base: unit (wg_n*2+wch), lane byte = wcl*1024 + lane31*16 + lhi*2048
  const char* bBw = (const char*)(wsB + (long)(wg_n * 2 + wch) * NT * 1024)
                  + wcl * 1024 + lane31 * 16 + lhi * 2048;

  f32x16 acc[4][2];
#pragma unroll
  for (int m = 0; m < 4; ++m)
#pragma unroll
    for (int n = 0; n < 2; ++n)
#pragma unroll
      for (int q = 0; q < 16; ++q) acc[m][n][q] = 0.f;

  bf16x8 aR[4], bR[4][2];

  // prologue: stage A(0) (4 loads) + load B(0) (8 loads); WAITV(6) retires
  // stA0,stA1,Bk0 -> leaves Bk1..3 = 6 = steady entering invariant.
  STAGE(0, 0, bA0, 0) STAGE(0, 1, bA1, 0)
  BLOAD(0, -1) BLOAD(1, -1) BLOAD(2, -1) BLOAD(3, -1)
  WAITV(6); BAR();

#pragma unroll 1
  for (int it = 0; it < 31; ++it) {            // tiles 0..61
    const int t = 2 * it;
    TILE(pA0, 1, t,     1, WAITV(10), WAITV(10), WAITV(10), WAITV(6))
    TILE(pA1, 0, t + 1, 1, WAITV(10), WAITV(10), WAITV(10), WAITV(6))
  }
  TILE(pA0, 1, 62, 1, WAITV(10), WAITV(10), WAITV(10), WAITV(6))
  TILE(pA1, 0, 63, 0, WAITV(4),  WAITV(2),  WAITV(0),  )

  // epilogue: out = acc * scale[col]
  // 32x32 C/D map (m74/m101): col = lane&31, row = (reg&3)+8*(reg>>2)+4*(lane>>5)
  const int col0 = wg_n * BN + wc * 64 + lane31;
  const int row0 = wg_m * BM + wr * 128 + lhi * 4;
#pragma unroll
  for (int nt = 0; nt < 2; ++nt) {
    const int col = col0 + nt * 32;
    const float s = Scale[col];
#pragma unroll
    for (int mt = 0; mt < 4; ++mt) {
      const int rb = row0 + mt * 32;
#pragma unroll
      for (int q = 0; q < 4; ++q)
#pragma unroll
        for (int j = 0; j < 4; ++j)
          Out[(long)(rb + q * 8 + j) * DOUT + col] = acc[mt][nt][q * 4 + j] * s;
    }
  }
}

// ================= fallback: fused 128x128 (round-1, proven) =================
__global__ __launch_bounds__(256, 2) void gemm_fused_kernel(
    const float* __restrict__ X, const int* __restrict__ W,
    const int* __restrict__ Off, const float* __restrict__ Scale,
    float* __restrict__ Out) {
  __shared__ char ldsA[2][128 * 64 * 2];
  __shared__ char ldsB[2][128 * 64 * 2];

  const int tid  = threadIdx.x;
  const int lane = tid & 63;
  const int wid  = tid >> 6;
  const int fwr  = wid >> 1;
  const int fwc  = wid & 1;

  int gid = (int)blockIdx.x;
  gid = (gid & 7) * (2048 >> 3) + (gid >> 3);
  const int wg_m = gid / 32;
  const int wg_n = gid % 32;
  const int brow = wg_m * 128;
  const int bcol = wg_n * 128;

  f32x4 acc[4][4];
#pragma unroll
  for (int m = 0; m < 4; ++m)
#pragma unroll
    for (int n = 0; n < 4; ++n) acc[m][n] = (f32x4){0.f, 0.f, 0.f, 0.f};

  int aoff[2][4], boff[2][4];
#pragma unroll
  for (int kk = 0; kk < 2; ++kk)
#pragma unroll
    for (int m = 0; m < 4; ++m) {
      const int kb = kk * 64 + ((lane >> 4) << 4);
      const int ra = fwr * 64 + m * 16 + (lane & 15);
      const int rb = fwc * 64 + m * 16 + (lane & 15);
      aoff[kk][m] = ra * 128 + (kb ^ ((ra & 7) << 4));
      boff[kk][m] = rb * 128 + (kb ^ ((rb & 7) << 4));
    }

  long xo[8], wo[8];
  int lo[8], ofv[8];
#pragma unroll
  for (int i = 0; i < 8; ++i) {
    const int idx = tid + i * 256;
    const int row = idx >> 4, c4 = idx & 15;
    xo[i] = (long)(brow + row) * DIN + c4 * 4;
    wo[i] = (long)(bcol + row) * DIN + c4 * 4;
    lo[i] = row * 128 + ((c4 * 8) ^ ((row & 7) << 4));
    ofv[i] = Off[bcol + row];
  }
  {
#pragma unroll
    for (int i = 0; i < 8; ++i) {
      f32x4 f = *(const f32x4*)(X + xo[i]);
      u32x2 d;
      d[0] = pack_bf2_rne(f[0], f[1]);
      d[1] = pack_bf2_rne(f[2], f[3]);
      *(u32x2*)(&ldsA[0][lo[i]]) = d;
    }
#pragma unroll
    for (int i = 0; i < 8; ++i) {
      i32x4 w = *(const i32x4*)(W + wo[i]);
      u32x2 d;
      d[0] = pack_bf2_exact(w[0] - ofv[i], w[1] - ofv[i]);
      d[1] = pack_bf2_exact(w[2] - ofv[i], w[3] - ofv[i]);
      *(u32x2*)(&ldsB[0][lo[i]]) = d;
    }
  }
  __syncthreads();
#pragma unroll 1
  for (int kt = 0; kt < NT; ++kt) {
    const int cur = kt & 1;
    const bool pf = (kt + 1 < NT);
    f32x4 fa[8];
    i32x4 fb[8];
    if (pf) {
      const int ko = (kt + 1) * 64;
#pragma unroll
      for (int i = 0; i < 8; ++i) fa[i] = *(const f32x4*)(X + xo[i] + ko);
#pragma unroll
      for (int i = 0; i < 8; ++i) fb[i] = *(const i32x4*)(W + wo[i] + ko);
    }
#pragma unroll
    for (int kk = 0; kk < 2; ++kk) {
      bf16x8 fa2[4], fb2[4];
#pragma unroll
      for (int m = 0; m < 4; ++m)
        fa2[m] = __builtin_bit_cast(bf16x8, *(const u32x4*)(&ldsA[cur][aoff[kk][m]]));
#pragma unroll
      for (int n = 0; n < 4; ++n)
        fb2[n] = __builtin_bit_cast(bf16x8, *(const u32x4*)(&ldsB[cur][boff[kk][n]]));
#pragma unroll
      for (int m = 0; m < 4; ++m)
#pragma unroll
        for (int n = 0; n < 4; ++n)
          acc[m][n] = __builtin_amdgcn_mfma_f32_16x16x32_bf16(fa2[m], fb2[n], acc[m][n], 0, 0, 0);
    }
    if (pf) {
      char* dA = ldsA[cur ^ 1];
      char* dB = ldsB[cur ^ 1];
#pragma unroll
      for (int i = 0; i < 8; ++i) {
        u32x2 d;
        d[0] = pack_bf2_rne(fa[i][0], fa[i][1]);
        d[1] = pack_bf2_rne(fa[i][2], fa[i][3]);
        *(u32x2*)(&dA[lo[i]]) = d;
      }
#pragma unroll
      for (int i = 0; i < 8; ++i) {
        u32x2 d;
        d[0] = pack_bf2_exact(fb[i][0] - ofv[i], fb[i][1] - ofv[i]);
        d[1] = pack_bf2_exact(fb[i][2] - ofv[i], fb[i][3] - ofv[i]);
        *(u32x2*)(&dB[lo[i]]) = d;
      }
    }
    __syncthreads();
  }

  const int col0 = bcol + fwc * 64 + (lane & 15);
  const int row0 = brow + fwr * 64 + ((lane >> 4) << 2);
#pragma unroll
  for (int n = 0; n < 4; ++n) {
    const int col = col0 + n * 16;
    const float s = Scale[col];
#pragma unroll
    for (int m = 0; m < 4; ++m) {
      const int r = row0 + m * 16;
#pragma unroll
      for (int j = 0; j < 4; ++j)
        Out[(long)(r + j) * DOUT + col] = acc[m][n][j] * s;
    }
  }
}

extern "C" void kernel_launch(void* const* d_in, const int* in_sizes, int n_in,
                              void* d_out, int out_size, void* d_ws, size_t ws_size,
                              hipStream_t stream) {
  (void)in_sizes; (void)n_in; (void)out_size;
  const float* X  = (const float*)d_in[0];
  const int*   W  = (const int*)d_in[1];
  const float* Sc = (const float*)d_in[2];
  const int*   Of = (const int*)d_in[3];
  float* Out = (float*)d_out;

  const size_t needA = (size_t)MTOT * DIN * 2;
  const size_t needB = (size_t)DOUT * DIN * 2;
  if (ws_size >= needA + needB) {
    u32x4* wsA = (u32x4*)d_ws;
    u32x4* wsB = (u32x4*)((char*)d_ws + needA);
    conv_kernel<<<3072, 256, 0, stream>>>(X, wsA, W, Of, wsB);
    gemm8_kernel<<<NWG, 512, 0, stream>>>(wsA, wsB, Sc, Out);
  } else {
    gemm_fused_kernel<<<2048, 256, 0, stream>>>(X, W, Of, Sc, Out);
  }
}